// Round 6
// baseline (107.476 us; speedup 1.0000x reference)
//
#include <hip/hip_runtime.h>
#include <math.h>

#define BB 1024
#define DD 128
#define QQ 65536
#define CHUNK 32
#define THREADS 256
#define COLS_PER_BLOCK 256
#define F2G (BB / COLS_PER_BLOCK)   // 4
#define NSLICES 256
#define INV_T 14.285714285714286f
#define SCALE 20.609929155556627f   // (1/T) * log2(e)
#define LN2F 0.6931471805599453f

typedef short short8 __attribute__((ext_vector_type(8)));
typedef float f32x4  __attribute__((ext_vector_type(4)));
typedef unsigned short us4 __attribute__((ext_vector_type(4)));

#if __has_builtin(__builtin_amdgcn_exp2f)
#define EXP2F(x) __builtin_amdgcn_exp2f(x)
#else
#define EXP2F(x) exp2f(x)
#endif

static __device__ __forceinline__ unsigned short bf16rne(float f) {
    union { float f; unsigned u; } v; v.f = f;
    unsigned r = (v.u + 0x7FFFu + ((v.u >> 16) & 1u)) >> 16;
    return (unsigned short)r;
}

static __device__ __forceinline__ short8 pack8s(float4 x, float4 y) { // scaled
    short8 r;
    r[0]=(short)bf16rne(x.x*SCALE); r[1]=(short)bf16rne(x.y*SCALE);
    r[2]=(short)bf16rne(x.z*SCALE); r[3]=(short)bf16rne(x.w*SCALE);
    r[4]=(short)bf16rne(y.x*SCALE); r[5]=(short)bf16rne(y.y*SCALE);
    r[6]=(short)bf16rne(y.z*SCALE); r[7]=(short)bf16rne(y.w*SCALE);
    return r;
}
static __device__ __forceinline__ short8 pack8(float4 x, float4 y) { // unscaled
    short8 r;
    r[0]=(short)bf16rne(x.x); r[1]=(short)bf16rne(x.y);
    r[2]=(short)bf16rne(x.z); r[3]=(short)bf16rne(x.w);
    r[4]=(short)bf16rne(y.x); r[5]=(short)bf16rne(y.y);
    r[6]=(short)bf16rne(y.z); r[7]=(short)bf16rne(y.w);
    return r;
}

// ---------- prep: qbf convert + qlabn + cnt histogram + srr ----------
// grid 516: blocks 0..511 convert (blocks 0..255 also labels/histogram);
// blocks 512..515 compute srr (one thread per batch row).
template<int PRE>
__global__ __launch_bounds__(256)
void k_prep(const float* __restrict__ features, const int* __restrict__ labels,
            const float* __restrict__ queue, const int* __restrict__ queue_labels,
            unsigned short* __restrict__ qbf, int* __restrict__ qlabn,
            int* __restrict__ cnt, float* __restrict__ srr)
{
    const int bid = blockIdx.x;
    const int t = bid * 256 + threadIdx.x;
    if (bid < 512) {
        if (PRE) {
#pragma unroll
            for (int k = 0; k < 16; ++k) {
                int u = k * 131072 + t;          // us4 index
                int e = u * 4;                   // element index
                int row = e >> 7;
                const float* src = (row < BB)
                    ? (features + (size_t)row * 2 * DD + (e & 127))
                    : (queue + ((size_t)e - (size_t)BB * DD));
                float4 v = *reinterpret_cast<const float4*>(src);
                us4 pk;
                pk[0] = bf16rne(v.x); pk[1] = bf16rne(v.y);
                pk[2] = bf16rne(v.z); pk[3] = bf16rne(v.w);
                *reinterpret_cast<us4*>(qbf + (size_t)e) = pk;
            }
        }
        if (bid < 256) {
            int lab = (t < BB) ? labels[t] : queue_labels[t - BB];
            if (PRE) qlabn[t] = lab;
            atomicAdd(&cnt[lab], 1);
        }
    } else {
        int r = t - 512 * 256;                   // 0..1023
        const float* f2p = features + (size_t)r * 2 * DD + DD;
        const float* f1p = features + (size_t)r * 2 * DD;
        float d = 0.f;
#pragma unroll
        for (int k = 0; k < DD / 4; ++k) {
            float4 a = reinterpret_cast<const float4*>(f2p)[k];
            float4 b = reinterpret_cast<const float4*>(f1p)[k];
            d += a.x * b.x + a.y * b.y + a.z * b.z + a.w * b.w;
        }
        srr[r] = d;
    }
}

// ---------- main: tot/pose/psum via MFMA, atomic accumulate to rowacc[1024][4] ----------
template<int PRE>
__global__ __launch_bounds__(THREADS)
void supcon_main(const float* __restrict__ features, const int* __restrict__ labels,
                 const float* __restrict__ queue, const int* __restrict__ queue_labels,
                 const unsigned short* __restrict__ qbf, const int* __restrict__ qlabn,
                 float* __restrict__ rowacc, int nslices)
{
    __shared__ int4 ldsbuf[2][512];   // 2 x 8KB bf16 A-chunks [32][128], swizzled

    const int tid = threadIdx.x;
    const int l = tid & 63, w = tid >> 6;
    const int bid = blockIdx.x;
    const int slice = bid % nslices, f2g = bid / nslices;
    const int sliceRows = QQ / nslices;
    const int nchunks = sliceRows / CHUNK;
    const int colbase = f2g * COLS_PER_BLOCK + w * 64;

    // stationary B operand: 4x16 f2 cols, scaled bf16 packed from f32 (once per block)
    short8 bf[4][4];
    int mylab[4];
#pragma unroll
    for (int b = 0; b < 4; ++b) {
        int r = colbase + b * 16 + (l & 15);
        mylab[b] = labels[r];
        const float* fp = features + (size_t)r * 2 * DD + DD + ((l >> 4) * 8);
#pragma unroll
        for (int kk = 0; kk < 4; ++kk) {
            float4 x = *reinterpret_cast<const float4*>(fp + kk * 32);
            float4 y = *reinterpret_cast<const float4*>(fp + kk * 32 + 4);
            bf[b][kk] = pack8s(x, y);
        }
    }

    float tot[4]  = {0.f,0.f,0.f,0.f};
    float pose[4] = {0.f,0.f,0.f,0.f};
    float psum[4] = {0.f,0.f,0.f,0.f};

    const int srow_ = tid >> 3, sseg = tid & 7;
    const int swzs = (srow_ & 7) << 4;
    const int j0base = slice * sliceRows;

    // prologue: stage chunk 0
    {
        int j = j0base + srow_;
        char* base = (char*)&ldsbuf[0][0] + srow_ * 256;
        int cb0 = (sseg * 32) ^ swzs;
        if (PRE) {
            const short8* src = reinterpret_cast<const short8*>(
                qbf + (size_t)j * DD + sseg * 16);
            *reinterpret_cast<short8*>(base + cb0)        = src[0];
            *reinterpret_cast<short8*>(base + (cb0 ^ 16)) = src[1];
        } else {
            const float* src = ((j < BB) ? (features + (size_t)j * 2 * DD)
                                         : (queue + (size_t)(j - BB) * DD)) + sseg * 16;
            float4 p0 = reinterpret_cast<const float4*>(src)[0];
            float4 p1 = reinterpret_cast<const float4*>(src)[1];
            float4 p2 = reinterpret_cast<const float4*>(src)[2];
            float4 p3 = reinterpret_cast<const float4*>(src)[3];
            *reinterpret_cast<short8*>(base + cb0)        = pack8(p0, p1);
            *reinterpret_cast<short8*>(base + (cb0 ^ 16)) = pack8(p2, p3);
        }
    }

    int cur = 0;
    for (int c = 0; c < nchunks; ++c) {
        __syncthreads();
        const int cj0 = j0base + c * CHUNK;
        const bool havenext = (c + 1 < nchunks);

        // issue next chunk's loads early (T14)
        short8 nlo, nhi;
        float4 p0, p1, p2, p3;
        if (havenext) {
            int j = cj0 + CHUNK + srow_;
            if (PRE) {
                const short8* src = reinterpret_cast<const short8*>(
                    qbf + (size_t)j * DD + sseg * 16);
                nlo = src[0]; nhi = src[1];
            } else {
                const float* src = ((j < BB) ? (features + (size_t)j * 2 * DD)
                                             : (queue + (size_t)(j - BB) * DD)) + sseg * 16;
                p0 = reinterpret_cast<const float4*>(src)[0];
                p1 = reinterpret_cast<const float4*>(src)[1];
                p2 = reinterpret_cast<const float4*>(src)[2];
                p3 = reinterpret_cast<const float4*>(src)[3];
            }
        }

        // compute from buf[cur]
        const char* abase = (const char*)&ldsbuf[cur][0];
#pragma unroll
        for (int t2 = 0; t2 < 2; ++t2) {
            const int row = t2 * 16 + (l & 15);
            const char* rbase = abase + row * 256;
            const int g16 = (l >> 4) * 16;
            const int swz = (row & 7) << 4;
            // hoisted swizzled bases; kk offsets become immediate 0/128
            const char* pA = rbase + (g16 ^ swz);
            const char* pB = rbase + ((64 + g16) ^ swz);
            short8 a0 = *reinterpret_cast<const short8*>(pA);
            short8 a1 = *reinterpret_cast<const short8*>(pB);
            short8 a2 = *reinterpret_cast<const short8*>(pA + 128);
            short8 a3 = *reinterpret_cast<const short8*>(pB + 128);

            const int j0 = cj0 + t2 * 16 + ((l >> 4) << 2);
            int4 ql4;
            if (PRE) ql4 = *reinterpret_cast<const int4*>(qlabn + j0);
            else ql4 = (j0 < BB) ? *reinterpret_cast<const int4*>(labels + j0)
                                 : *reinterpret_cast<const int4*>(queue_labels + (j0 - BB));
            const int* ql = reinterpret_cast<const int*>(&ql4);

            f32x4 acc[4];
#pragma unroll
            for (int b = 0; b < 4; ++b) {
                acc[b] = f32x4{0.f,0.f,0.f,0.f};
                acc[b] = __builtin_amdgcn_mfma_f32_16x16x32_bf16(a0, bf[b][0], acc[b], 0, 0, 0);
                acc[b] = __builtin_amdgcn_mfma_f32_16x16x32_bf16(a1, bf[b][1], acc[b], 0, 0, 0);
                acc[b] = __builtin_amdgcn_mfma_f32_16x16x32_bf16(a2, bf[b][2], acc[b], 0, 0, 0);
                acc[b] = __builtin_amdgcn_mfma_f32_16x16x32_bf16(a3, bf[b][3], acc[b], 0, 0, 0);
            }
#pragma unroll
            for (int b = 0; b < 4; ++b) {
#pragma unroll
                for (int reg = 0; reg < 4; ++reg) {
                    float a = acc[b][reg];
                    float e = EXP2F(a);                      // a = s*log2(e)
                    float pf = (ql[reg] == mylab[b]) ? 1.0f : 0.0f;
                    tot[b]  += e;
                    pose[b]  = fmaf(pf, e, pose[b]);
                    psum[b]  = fmaf(pf, a, psum[b]);
                }
            }
        }

        // write next chunk into other buffer
        if (havenext) {
            char* base = (char*)&ldsbuf[cur ^ 1][0] + srow_ * 256;
            int cb0 = (sseg * 32) ^ swzs;
            if (PRE) {
                *reinterpret_cast<short8*>(base + cb0)        = nlo;
                *reinterpret_cast<short8*>(base + (cb0 ^ 16)) = nhi;
            } else {
                *reinterpret_cast<short8*>(base + cb0)        = pack8(p0, p1);
                *reinterpret_cast<short8*>(base + (cb0 ^ 16)) = pack8(p2, p3);
            }
            cur ^= 1;
        }
    }

#pragma unroll
    for (int b = 0; b < 4; ++b) {
#pragma unroll
        for (int off = 16; off <= 32; off <<= 1) {
            tot[b]  += __shfl_xor(tot[b],  off);
            pose[b] += __shfl_xor(pose[b], off);
            psum[b] += __shfl_xor(psum[b], off);
        }
    }
    if (l < 16) {
#pragma unroll
        for (int b = 0; b < 4; ++b) {
            float* dst = rowacc + (size_t)(colbase + b * 16 + l) * 4;
            atomicAdd(dst + 0, tot[b]);
            atomicAdd(dst + 1, pose[b]);
            atomicAdd(dst + 2, psum[b]);
        }
    }
}

// ---------- finish: per-row log terms, two scalars, last block writes out ----------
__global__ __launch_bounds__(256)
void f_finish(const float* __restrict__ rowacc, const float* __restrict__ srr,
              const int* __restrict__ cnt, const int* __restrict__ labels,
              float* __restrict__ scal, int* __restrict__ ticket,
              float* __restrict__ out)
{
    __shared__ float red[4][2];
    const int r = blockIdx.x * 256 + threadIdx.x;
    const int wv = threadIdx.x >> 6, lane = threadIdx.x & 63;

    float4 v = reinterpret_cast<const float4*>(rowacc)[r];
    float tot = v.x, pose = v.y, ps = v.z;
    float srow = srr[r] * INV_T;                 // exact diag logit
    float trip = srow - logf(tot - expf(srow));
    float wgt  = 1.f / (float)(cnt[labels[r]] - 1);
    float mlpp = (ps * LN2F - srow) * wgt - logf(tot - pose);

#pragma unroll
    for (int off = 32; off > 0; off >>= 1) {
        trip += __shfl_xor(trip, off);
        mlpp += __shfl_xor(mlpp, off);
    }
    if (lane == 0) { red[wv][0] = trip; red[wv][1] = mlpp; }
    __syncthreads();
    if (threadIdx.x == 0) {
        atomicAdd(&scal[0], red[0][0] + red[1][0] + red[2][0] + red[3][0]);
        atomicAdd(&scal[1], red[0][1] + red[1][1] + red[2][1] + red[3][1]);
        __threadfence();
        int old = atomicAdd(ticket, 1);
        if (old == 3) {
            float aT = atomicAdd(&scal[0], 0.f);
            float aM = atomicAdd(&scal[1], 0.f);
            float selfl  = -aT / (float)BB;
            float classl = -aM / (float)BB;
            out[0] = 0.5f * (selfl + classl);
            out[1] = selfl;
            out[2] = classl;
        }
    }
}

extern "C" void kernel_launch(void* const* d_in, const int* in_sizes, int n_in,
                              void* d_out, int out_size, void* d_ws, size_t ws_size,
                              hipStream_t stream)
{
    const float* features     = (const float*)d_in[0];
    const int*   labels       = (const int*)  d_in[1];
    const float* queue        = (const float*)d_in[2];
    const int*   queue_labels = (const int*)  d_in[3];
    char* ws = (char*)d_ws;

    // ws layout (zeroed region first):
    //   cnt    4096
    //   scal   128   (accT, accM)
    //   ticket 128
    //   rowacc 1024*4*4 = 16384
    //   srr    4096
    //   [pre]  qbf 16MB, qlabn 256KB
    const size_t cnt_off    = 0;
    const size_t scal_off   = 4096;
    const size_t ticket_off = 4096 + 128;
    const size_t rowacc_off = 4096 + 256;
    const size_t zero_sz    = rowacc_off + 16384;
    const size_t srr_off    = zero_sz;
    const size_t qbf_off    = srr_off + 4096;
    const size_t qbf_sz     = (size_t)QQ * DD * 2;   // 16 MB
    const size_t qlabn_off  = qbf_off + qbf_sz;
    const size_t total_pre  = qlabn_off + (size_t)QQ * 4;

    const bool pre = ws_size >= total_pre;

    int*   cnt    = (int*)(ws + cnt_off);
    float* scal   = (float*)(ws + scal_off);
    int*   ticket = (int*)(ws + ticket_off);
    float* rowacc = (float*)(ws + rowacc_off);
    float* srr    = (float*)(ws + srr_off);
    unsigned short* qbf = pre ? (unsigned short*)(ws + qbf_off) : nullptr;
    int* qlabn          = pre ? (int*)(ws + qlabn_off) : nullptr;

    hipMemsetAsync(ws, 0, zero_sz, stream);

    if (pre)
        k_prep<1><<<dim3(516), dim3(256), 0, stream>>>(
            features, labels, queue, queue_labels, qbf, qlabn, cnt, srr);
    else
        k_prep<0><<<dim3(516), dim3(256), 0, stream>>>(
            features, labels, queue, queue_labels, qbf, qlabn, cnt, srr);

    const int nslices = NSLICES;
    dim3 grid(F2G * nslices);
    if (pre)
        supcon_main<1><<<grid, dim3(THREADS), 0, stream>>>(
            features, labels, queue, queue_labels, qbf, qlabn, rowacc, nslices);
    else
        supcon_main<0><<<grid, dim3(THREADS), 0, stream>>>(
            features, labels, queue, queue_labels, qbf, qlabn, rowacc, nslices);

    f_finish<<<dim3(4), dim3(256), 0, stream>>>(
        rowacc, srr, cnt, labels, scal, ticket, (float*)d_out);
}